// Round 16
// baseline (692.032 us; speedup 1.0000x reference)
//
#include <hip/hip_runtime.h>
#include <hip/hip_bf16.h>

#define D_   64
#define L_   6
#define B_   4
#define K_   256
#define NN   20000
#define EE   200000
#define RR   200
#define ER_  4000
#define EPS_ 1e-5f

typedef unsigned short u16;
typedef unsigned int   u32;
typedef short bf16x8 __attribute__((ext_vector_type(8)));
typedef float f32x4  __attribute__((ext_vector_type(4)));

__device__ __forceinline__ u16 f2bf(float f) {          // RNE f32 -> bf16
    u32 u = __float_as_uint(f);
    u += 0x7FFF + ((u >> 16) & 1);
    return (u16)(u >> 16);
}
__device__ __forceinline__ u32 pack2bf(float a, float b) {
    return (u32)f2bf(a) | ((u32)f2bf(b) << 16);
}
__device__ __forceinline__ float bflo(u32 u) { return __uint_as_float(u << 16); }
__device__ __forceinline__ float bfhi(u32 u) { return __uint_as_float(u & 0xFFFF0000u); }

// ================= CSR build (both graphs per dispatch) =================
__global__ __launch_bounds__(256)
void k_zero2(int* __restrict__ ec, int* __restrict__ rc) {
    int i = blockIdx.x * 256 + threadIdx.x;
    if (i < NN) ec[i] = 0;
    else if (i < NN + RR) rc[i - NN] = 0;
}

__global__ __launch_bounds__(256)
void k_hist2(const int* __restrict__ ei, const int* __restrict__ rei,
             int* __restrict__ ec, int* __restrict__ rc) {
    int g = blockIdx.x * 256 + threadIdx.x;
    if (g < EE) atomicAdd(&ec[ei[EE + g]], 1);
    else if (g < EE + ER_) atomicAdd(&rc[rei[ER_ + (g - EE)]], 1);
}

__global__ __launch_bounds__(256)
void k_scan1_2(const int* __restrict__ e_counts, int* __restrict__ e_pre, int* __restrict__ e_bs,
               const int* __restrict__ r_counts, int* __restrict__ r_pre, int* __restrict__ r_bs,
               int ent_nb) {
    __shared__ int tsum[256];
    const int* counts; int* pre; int* bs; int n; int blk;
    if ((int)blockIdx.x < ent_nb) { counts = e_counts; pre = e_pre; bs = e_bs; n = NN; blk = blockIdx.x; }
    else                          { counts = r_counts; pre = r_pre; bs = r_bs; n = RR; blk = 0; }
    int tid = threadIdx.x;
    int base = blk * 1024 + tid * 4;
    int c0 = 0, c1 = 0, c2 = 0, c3 = 0;
    if (base + 0 < n) c0 = counts[base + 0];
    if (base + 1 < n) c1 = counts[base + 1];
    if (base + 2 < n) c2 = counts[base + 2];
    if (base + 3 < n) c3 = counts[base + 3];
    tsum[tid] = c0 + c1 + c2 + c3;
    __syncthreads();
    if (tid == 0) {
        int acc = 0;
        for (int i = 0; i < 256; i++) { int t = tsum[i]; tsum[i] = acc; acc += t; }
    }
    __syncthreads();
    int run = tsum[tid];
    if (base + 0 < n) pre[base + 0] = run; run += c0;
    if (base + 1 < n) pre[base + 1] = run; run += c1;
    if (base + 2 < n) pre[base + 2] = run; run += c2;
    if (base + 3 < n) pre[base + 3] = run; run += c3;
    if (tid == 255) bs[blk] = run;
}

__global__ __launch_bounds__(64)
void k_scan2_2(int* __restrict__ eb, int enb, int* __restrict__ etot,
               int* __restrict__ rb, int rnb, int* __restrict__ rtot) {
    if (threadIdx.x == 0) {
        int acc = 0;
        for (int i = 0; i < enb; i++) { int t = eb[i]; eb[i] = acc; acc += t; }
        *etot = acc;
    }
    if (threadIdx.x == 1) {
        int acc = 0;
        for (int i = 0; i < rnb; i++) { int t = rb[i]; rb[i] = acc; acc += t; }
        *rtot = acc;
    }
}

__global__ __launch_bounds__(256)
void k_scan3_2(int* __restrict__ e_rp, const int* __restrict__ e_bs, int* __restrict__ e_cur,
               int* __restrict__ r_rp, const int* __restrict__ r_bs, int* __restrict__ r_cur) {
    int i = blockIdx.x * 256 + threadIdx.x;
    if (i < NN) {
        int v = e_rp[i] + e_bs[i >> 10];
        e_rp[i] = v; e_cur[i] = v;
    } else if (i < NN + RR) {
        int j = i - NN;
        int v = r_rp[j] + r_bs[j >> 10];
        r_rp[j] = v; r_cur[j] = v;
    }
}

__global__ __launch_bounds__(256)
void k_fill2(const int* __restrict__ ei, const int* __restrict__ et,
             const int* __restrict__ rei, const int* __restrict__ ret,
             int* __restrict__ e_cur, int* __restrict__ r_cur,
             int* __restrict__ e_packed, int* __restrict__ r_packed) {
    int g = blockIdx.x * 256 + threadIdx.x;
    if (g < EE) {
        int pos = atomicAdd(&e_cur[ei[EE + g]], 1);
        e_packed[pos] = ei[g] | (et[g] << 15);
    } else if (g < EE + ER_) {
        int h = g - EE;
        int pos = atomicAdd(&r_cur[rei[ER_ + h]], 1);
        r_packed[pos] = rei[h] | (ret[h] << 15);
    }
}

// ========== fused layer v10: persistent blocks, W staged once ==============
// Block stages BOTH bf16 W halves once, then grid-strides over 4-node tiles:
// {prefetch rowptr+residual -> stage Xs + gather -> barrier -> 4 MFMA (both
// passes, no restage) -> LNbuf -> barrier -> LN epilogue}.
template<int NNODES, int MODE, bool FIRST>
__global__ __launch_bounds__(256, 6)
void k_layer10(const float* __restrict__ xin, float* __restrict__ xout,
               const u16* __restrict__ xbin, u16* __restrict__ xbout,
               const void* __restrict__ relv,
               const int* __restrict__ rowptr, const int* __restrict__ packed,
               const float* __restrict__ query, const int* __restrict__ batch,
               const float* __restrict__ W, const float* __restrict__ bias,
               const float* __restrict__ gw, const float* __restrict__ bt,
               int ntiles) {
    __shared__ u16 Wt[2][64][72];    // both W halves, transposed [n][k], bf16
    __shared__ u16 As[16][72];       // message tile (bf16)
    __shared__ u16 Xs[16][72];       // x tile (bf16)
    __shared__ float LNbuf[16][65];  // f32 GEMM out for cross-wave LN
    const int tid   = threadIdx.x;
    const int lane  = tid & 63;
    const int wv    = tid >> 6;      // 0..3

    int bn0 = batch[0 * K_ * 3 + (MODE ? 0 : 2)];
    int bn1 = batch[1 * K_ * 3 + (MODE ? 0 : 2)];
    int bn2 = batch[2 * K_ * 3 + (MODE ? 0 : 2)];
    int bn3 = batch[3 * K_ * 3 + (MODE ? 0 : 2)];

    // ---- stage BOTH W halves (transposed + bf16), once per block ----
    #pragma unroll
    for (int half = 0; half < 2; half++) {
        int n = lane, k16 = wv * 16;
        u32 buf[8];
        #pragma unroll
        for (int j2 = 0; j2 < 8; j2++) {
            float w0 = W[(half * 64 + k16 + 2 * j2    ) * 64 + n];
            float w1 = W[(half * 64 + k16 + 2 * j2 + 1) * 64 + n];
            buf[j2] = pack2bf(w0, w1);
        }
        uint4* dst = reinterpret_cast<uint4*>(&Wt[half][n][k16]);
        dst[0] = make_uint4(buf[0], buf[1], buf[2], buf[3]);
        dst[1] = make_uint4(buf[4], buf[5], buf[6], buf[7]);
    }

    float qreg[4][8];
    const int slot = lane >> 3;   // edge slot 0..7
    const int d8   = lane & 7;    // 8-dim block
    if constexpr (MODE == 1) {
        #pragma unroll
        for (int b = 0; b < 4; b++) {
            float4 q0 = *reinterpret_cast<const float4*>(query + b * 64 + d8 * 8);
            float4 q1 = *reinterpret_cast<const float4*>(query + b * 64 + d8 * 8 + 4);
            qreg[b][0]=q0.x; qreg[b][1]=q0.y; qreg[b][2]=q0.z; qreg[b][3]=q0.w;
            qreg[b][4]=q1.x; qreg[b][5]=q1.y; qreg[b][6]=q1.z; qreg[b][7]=q1.w;
        }
    }

    const int erow = wv * 4 + (lane >> 4);   // 0..15 epilogue row
    const int tx   = lane & 15;
    const int al   = lane & 15;
    const int ag   = lane >> 4;

    for (int tile = blockIdx.x; tile < ntiles; tile += gridDim.x) {
        const int node0 = tile * 4;

        // ---- prefetch rowptr + f32 residual (overlap with staging/gather) --
        const int gnode = node0 + wv;
        int beg = 0, end = 0;
        if (gnode < NNODES) { beg = rowptr[gnode]; end = rowptr[gnode + 1]; }

        float4 resf = make_float4(0.f, 0.f, 0.f, 0.f);
        if constexpr (!FIRST) {
            int b = erow >> 2, nd = node0 + (erow & 3);
            if (nd < NNODES)
                resf = *reinterpret_cast<const float4*>(
                    xin + ((size_t)b * NNODES + nd) * 64 + tx * 4);
        }

        // ---- stage Xs <- x state (or implicit boundary): 128 items ----
        if (tid < 128) {
            int m = tid >> 3, o8 = (tid & 7) * 8;
            int b = m >> 2, node = node0 + (m & 3);
            uint4 v = make_uint4(0, 0, 0, 0);
            if (node < NNODES) {
                if constexpr (FIRST) {
                    int bnb = (b==0)?bn0:(b==1)?bn1:(b==2)?bn2:bn3;
                    if (node == bnb) {
                        if constexpr (MODE == 1) {
                            const float* q = query + b * 64 + o8;
                            v = make_uint4(pack2bf(q[0], q[1]), pack2bf(q[2], q[3]),
                                           pack2bf(q[4], q[5]), pack2bf(q[6], q[7]));
                        } else {
                            v = make_uint4(0x3F803F80u, 0x3F803F80u, 0x3F803F80u, 0x3F803F80u);
                        }
                    }
                } else if constexpr (MODE == 1) {
                    v = *reinterpret_cast<const uint4*>(
                        xbin + ((size_t)b * NNODES + node) * 64 + o8);
                } else {
                    const float* src = xin + ((size_t)b * NNODES + node) * 64 + o8;
                    float4 x0 = *reinterpret_cast<const float4*>(src);
                    float4 x1 = *reinterpret_cast<const float4*>(src + 4);
                    v = make_uint4(pack2bf(x0.x, x0.y), pack2bf(x0.z, x0.w),
                                   pack2bf(x1.x, x1.y), pack2bf(x1.z, x1.w));
                }
            }
            *reinterpret_cast<uint4*>(&Xs[m][o8]) = v;
        }

        // ---- gather: wave wv handles node gnode ----
        {
            float acc[4][8];
            #pragma unroll
            for (int b = 0; b < 4; b++)
                #pragma unroll
                for (int i = 0; i < 8; i++) acc[b][i] = 0.f;

            for (int e0 = beg; e0 < end; e0 += 16) {
                #pragma unroll
                for (int half = 0; half < 2; half++) {
                    int e = e0 + half * 8 + slot;
                    if (e < end) {
                        int p = packed[e];
                        int src = p & 0x7FFF;
                        int et  = p >> 15;
                        if constexpr (MODE == 1) {
                            const u16* rb = (const u16*)relv;
                            if constexpr (FIRST) {
                                #pragma unroll
                                for (int b = 0; b < 4; b++) {
                                    int bnb = (b==0)?bn0:(b==1)?bn1:(b==2)?bn2:bn3;
                                    if (src == bnb) {
                                        uint4 rv = *reinterpret_cast<const uint4*>(
                                            rb + ((size_t)(b * RR + et)) * 64 + d8 * 8);
                                        acc[b][0] = fmaf(qreg[b][0], bflo(rv.x), acc[b][0]);
                                        acc[b][1] = fmaf(qreg[b][1], bfhi(rv.x), acc[b][1]);
                                        acc[b][2] = fmaf(qreg[b][2], bflo(rv.y), acc[b][2]);
                                        acc[b][3] = fmaf(qreg[b][3], bfhi(rv.y), acc[b][3]);
                                        acc[b][4] = fmaf(qreg[b][4], bflo(rv.z), acc[b][4]);
                                        acc[b][5] = fmaf(qreg[b][5], bfhi(rv.z), acc[b][5]);
                                        acc[b][6] = fmaf(qreg[b][6], bflo(rv.w), acc[b][6]);
                                        acc[b][7] = fmaf(qreg[b][7], bfhi(rv.w), acc[b][7]);
                                    }
                                }
                            } else {
                                #pragma unroll
                                for (int b = 0; b < 4; b++) {
                                    uint4 xv = *reinterpret_cast<const uint4*>(
                                        xbin + ((size_t)(b * NNODES + src)) * 64 + d8 * 8);
                                    uint4 rv = *reinterpret_cast<const uint4*>(
                                        ((const u16*)relv) + ((size_t)(b * RR + et)) * 64 + d8 * 8);
                                    acc[b][0] = fmaf(bflo(xv.x), bflo(rv.x), acc[b][0]);
                                    acc[b][1] = fmaf(bfhi(xv.x), bfhi(rv.x), acc[b][1]);
                                    acc[b][2] = fmaf(bflo(xv.y), bflo(rv.y), acc[b][2]);
                                    acc[b][3] = fmaf(bfhi(xv.y), bfhi(rv.y), acc[b][3]);
                                    acc[b][4] = fmaf(bflo(xv.z), bflo(rv.z), acc[b][4]);
                                    acc[b][5] = fmaf(bfhi(xv.z), bfhi(rv.z), acc[b][5]);
                                    acc[b][6] = fmaf(bflo(xv.w), bflo(rv.w), acc[b][6]);
                                    acc[b][7] = fmaf(bfhi(xv.w), bfhi(rv.w), acc[b][7]);
                                }
                            }
                        } else {
                            const float* re = (const float*)relv;
                            if constexpr (FIRST) {
                                bool m0 = (src == bn0), m1 = (src == bn1),
                                     m2 = (src == bn2), m3 = (src == bn3);
                                if (m0 | m1 | m2 | m3) {
                                    float4 r0 = *reinterpret_cast<const float4*>(re + et * 64 + d8 * 8);
                                    float4 r1 = *reinterpret_cast<const float4*>(re + et * 64 + d8 * 8 + 4);
                                    float rr[8] = {r0.x,r0.y,r0.z,r0.w,r1.x,r1.y,r1.z,r1.w};
                                    if (m0) {
                                        #pragma unroll
                                        for (int i = 0; i < 8; i++) acc[0][i] += rr[i];
                                    }
                                    if (m1) {
                                        #pragma unroll
                                        for (int i = 0; i < 8; i++) acc[1][i] += rr[i];
                                    }
                                    if (m2) {
                                        #pragma unroll
                                        for (int i = 0; i < 8; i++) acc[2][i] += rr[i];
                                    }
                                    if (m3) {
                                        #pragma unroll
                                        for (int i = 0; i < 8; i++) acc[3][i] += rr[i];
                                    }
                                }
                            } else {
                                float4 r0 = *reinterpret_cast<const float4*>(re + et * 64 + d8 * 8);
                                float4 r1 = *reinterpret_cast<const float4*>(re + et * 64 + d8 * 8 + 4);
                                #pragma unroll
                                for (int b = 0; b < 4; b++) {
                                    const float* xr = xin + ((size_t)(b * NNODES + src)) * 64 + d8 * 8;
                                    float4 x0 = *reinterpret_cast<const float4*>(xr);
                                    float4 x1 = *reinterpret_cast<const float4*>(xr + 4);
                                    acc[b][0] = fmaf(x0.x, r0.x, acc[b][0]);
                                    acc[b][1] = fmaf(x0.y, r0.y, acc[b][1]);
                                    acc[b][2] = fmaf(x0.z, r0.z, acc[b][2]);
                                    acc[b][3] = fmaf(x0.w, r0.w, acc[b][3]);
                                    acc[b][4] = fmaf(x1.x, r1.x, acc[b][4]);
                                    acc[b][5] = fmaf(x1.y, r1.y, acc[b][5]);
                                    acc[b][6] = fmaf(x1.z, r1.z, acc[b][6]);
                                    acc[b][7] = fmaf(x1.w, r1.w, acc[b][7]);
                                }
                            }
                        }
                    }
                }
            }

            #pragma unroll
            for (int b = 0; b < 4; b++)
                #pragma unroll
                for (int i = 0; i < 8; i++) {
                    float v = acc[b][i];
                    v += __shfl_xor(v, 8);
                    v += __shfl_xor(v, 16);
                    v += __shfl_xor(v, 32);
                    acc[b][i] = v;
                }

            if (slot < 4) {
                float out[8];
                #pragma unroll
                for (int i = 0; i < 8; i++)
                    out[i] = (slot==0) ? acc[0][i] : (slot==1) ? acc[1][i]
                           : (slot==2) ? acc[2][i] : acc[3][i];
                int bnb = (slot==0)?bn0:(slot==1)?bn1:(slot==2)?bn2:bn3;
                if (gnode < NNODES && gnode == bnb) {
                    if constexpr (MODE == 1) {
                        #pragma unroll
                        for (int i = 0; i < 8; i++)
                            out[i] += (slot==0)?qreg[0][i]:(slot==1)?qreg[1][i]
                                     :(slot==2)?qreg[2][i]:qreg[3][i];
                    } else {
                        #pragma unroll
                        for (int i = 0; i < 8; i++) out[i] += 1.0f;
                    }
                }
                int m = slot * 4 + wv;
                *reinterpret_cast<uint4*>(&As[m][d8 * 8]) =
                    make_uint4(pack2bf(out[0], out[1]), pack2bf(out[2], out[3]),
                               pack2bf(out[4], out[5]), pack2bf(out[6], out[7]));
            }
        }
        __syncthreads();

        // ---- MFMA: both passes back-to-back (wave = n-tile) ----
        const int nt = wv;
        f32x4 acc4 = (f32x4){0.f, 0.f, 0.f, 0.f};
        {
            bf16x8 a0 = *reinterpret_cast<const bf16x8*>(&As[al][ag * 8]);
            bf16x8 a1 = *reinterpret_cast<const bf16x8*>(&As[al][32 + ag * 8]);
            bf16x8 b0 = *reinterpret_cast<const bf16x8*>(&Wt[1][nt * 16 + al][ag * 8]);
            bf16x8 b1 = *reinterpret_cast<const bf16x8*>(&Wt[1][nt * 16 + al][32 + ag * 8]);
            acc4 = __builtin_amdgcn_mfma_f32_16x16x32_bf16(a0, b0, acc4, 0, 0, 0);
            acc4 = __builtin_amdgcn_mfma_f32_16x16x32_bf16(a1, b1, acc4, 0, 0, 0);
            bf16x8 x0 = *reinterpret_cast<const bf16x8*>(&Xs[al][ag * 8]);
            bf16x8 x1 = *reinterpret_cast<const bf16x8*>(&Xs[al][32 + ag * 8]);
            bf16x8 d0 = *reinterpret_cast<const bf16x8*>(&Wt[0][nt * 16 + al][ag * 8]);
            bf16x8 d1 = *reinterpret_cast<const bf16x8*>(&Wt[0][nt * 16 + al][32 + ag * 8]);
            acc4 = __builtin_amdgcn_mfma_f32_16x16x32_bf16(x0, d0, acc4, 0, 0, 0);
            acc4 = __builtin_amdgcn_mfma_f32_16x16x32_bf16(x1, d1, acc4, 0, 0, 0);
        }
        #pragma unroll
        for (int reg = 0; reg < 4; reg++)
            LNbuf[ag * 4 + reg][nt * 16 + al] = acc4[reg];
        __syncthreads();

        // ---- epilogue: wave wv handles rows wv*4..wv*4+3 ----
        {
            int row = erow;
            int b = row >> 2, node = node0 + (row & 3);
            float o[4];
            float s1 = 0.f, s2 = 0.f;
            #pragma unroll
            for (int i = 0; i < 4; i++) {
                o[i] = LNbuf[row][tx * 4 + i] + bias[tx * 4 + i];
                s1 += o[i];
                s2 += o[i] * o[i];
            }
            s1 += __shfl_xor(s1, 1); s2 += __shfl_xor(s2, 1);
            s1 += __shfl_xor(s1, 2); s2 += __shfl_xor(s2, 2);
            s1 += __shfl_xor(s1, 4); s2 += __shfl_xor(s2, 4);
            s1 += __shfl_xor(s1, 8); s2 += __shfl_xor(s2, 8);
            float mean = s1 * (1.f / 64.f);
            float var  = s2 * (1.f / 64.f) - mean * mean;
            float inv  = rsqrtf(var + EPS_);
            if (node < NNODES) {
                int bnb = (b==0)?bn0:(b==1)?bn1:(b==2)?bn2:bn3;
                size_t ro = ((size_t)b * NNODES + node) * 64;
                float r[4] = {resf.x, resf.y, resf.z, resf.w};
                if constexpr (FIRST) {
                    r[0] = r[1] = r[2] = r[3] = 0.f;
                    if (node == bnb) {
                        if constexpr (MODE == 1) {
                            float4 q = *reinterpret_cast<const float4*>(query + b * 64 + tx * 4);
                            r[0] = q.x; r[1] = q.y; r[2] = q.z; r[3] = q.w;
                        } else {
                            r[0] = r[1] = r[2] = r[3] = 1.0f;
                        }
                    }
                }
                float nv[4];
                #pragma unroll
                for (int i = 0; i < 4; i++) {
                    float h = (o[i] - mean) * inv * gw[tx * 4 + i] + bt[tx * 4 + i];
                    h = fmaxf(h, 0.f);
                    nv[i] = r[i] + h;
                }
                *reinterpret_cast<float4*>(&xout[ro + tx * 4]) =
                    make_float4(nv[0], nv[1], nv[2], nv[3]);
                if constexpr (MODE == 1) {
                    ushort4 b4;
                    b4.x = f2bf(nv[0]); b4.y = f2bf(nv[1]);
                    b4.z = f2bf(nv[2]); b4.w = f2bf(nv[3]);
                    *reinterpret_cast<ushort4*>(&xbout[ro + tx * 4]) = b4;
                }
            }
        }
    }
}

// ========== all-layer relation MLP: rel_all[l] = relu(rel_repr@Wp1+b)@Wp2+b (bf16)
__global__ __launch_bounds__(64)
void k_rel_mlp_all(const float* __restrict__ rel_repr,
                   const float* __restrict__ Wp1, const float* __restrict__ bp1,
                   const float* __restrict__ Wp2, const float* __restrict__ bp2,
                   u16* __restrict__ out) {
    __shared__ float rowv[64];
    __shared__ float hid[64];
    int l     = blockIdx.x / (B_ * RR);
    int rowid = blockIdx.x % (B_ * RR);
    int d = threadIdx.x;
    const float* w1 = Wp1 + l * 4096;
    const float* w2 = Wp2 + l * 4096;
    rowv[d] = rel_repr[rowid * 64 + d];
    __syncthreads();
    float acc = bp1[l * 64 + d];
    for (int k = 0; k < 64; k++) acc = fmaf(rowv[k], w1[k * 64 + d], acc);
    hid[d] = fmaxf(acc, 0.f);
    __syncthreads();
    float o = bp2[l * 64 + d];
    for (int k = 0; k < 64; k++) o = fmaf(hid[k], w2[k * 64 + d], o);
    out[(size_t)l * B_ * RR * 64 + rowid * 64 + d] = f2bf(o);
}

// ================= query[b] = rel_repr[b, r_index[b]] ======================
__global__ __launch_bounds__(256)
void k_query(const float* __restrict__ rel_repr, const int* __restrict__ batch,
             float* __restrict__ query) {
    int tid = threadIdx.x;  // 256 = B*64
    int b = tid >> 6;
    int d = tid & 63;
    int r = batch[b * K_ * 3 + 2];
    query[b * 64 + d] = rel_repr[(b * RR + r) * 64 + d];
}

// ================= final MLP over gathered rows ============================
__global__ __launch_bounds__(128)
void k_final(const float* __restrict__ x, const float* __restrict__ query,
             const int* __restrict__ batch,
             const float* __restrict__ W1, const float* __restrict__ b1,
             const float* __restrict__ W2, const float* __restrict__ b2,
             float* __restrict__ out) {
    __shared__ float feat[128];
    __shared__ float partial[2];
    int pair = blockIdx.x;          // b*K + k
    int b = pair / K_;
    int t = batch[pair * 3 + 1];
    int d = threadIdx.x;
    feat[d] = (d < 64) ? x[(size_t)(b * NN + t) * 64 + d] : query[b * 64 + (d - 64)];
    __syncthreads();
    float h = b1[d];
    for (int i = 0; i < 128; i++) h = fmaf(feat[i], W1[i * 128 + d], h);
    h = fmaxf(h, 0.f);
    float v = h * W2[d];
    #pragma unroll
    for (int off = 1; off < 64; off <<= 1) v += __shfl_xor(v, off);
    if ((d & 63) == 0) partial[d >> 6] = v;
    __syncthreads();
    if (d == 0) out[pair] = partial[0] + partial[1] + b2[0];
}

extern "C" void kernel_launch(void* const* d_in, const int* in_sizes, int n_in,
                              void* d_out, int out_size, void* d_ws, size_t ws_size,
                              hipStream_t stream) {
    const int* batch      = (const int*)d_in[0];
    const int* edge_index = (const int*)d_in[1];
    const int* edge_type  = (const int*)d_in[2];
    const int* rel_ei     = (const int*)d_in[3];
    const int* rel_et     = (const int*)d_in[4];
    const float* rel_emb = (const float*)d_in[7];
    const float* Wr  = (const float*)d_in[8];
    const float* br  = (const float*)d_in[9];
    const float* gr  = (const float*)d_in[10];
    const float* btr = (const float*)d_in[11];
    const float* Wp1 = (const float*)d_in[12];
    const float* bp1 = (const float*)d_in[13];
    const float* Wp2 = (const float*)d_in[14];
    const float* bp2 = (const float*)d_in[15];
    const float* We  = (const float*)d_in[16];
    const float* be  = (const float*)d_in[17];
    const float* ge  = (const float*)d_in[18];
    const float* bte = (const float*)d_in[19];
    const float* W1  = (const float*)d_in[20];
    const float* b1  = (const float*)d_in[21];
    const float* W2  = (const float*)d_in[22];
    const float* b2  = (const float*)d_in[23];

    float* ws = (float*)d_ws;
    float* rel_buf0 = ws;                              // 51200
    float* rel_buf1 = rel_buf0 + 51200;                // 51200
    float* query    = rel_buf1 + 51200;                // 256
    float* x0       = query + 256;                     // 5,120,000
    float* x1       = x0 + (size_t)B_ * NN * 64;       // 5,120,000
    u16*   xb0      = (u16*)(x1 + (size_t)B_ * NN * 64);          // 5.12M u16
    u16*   xb1      = xb0 + (size_t)B_ * NN * 64;                 // 5.12M u16
    u16*   rel_all  = xb1 + (size_t)B_ * NN * 64;                 // L*B*RR*64 u16
    int*   iw       = (int*)(rel_all + (size_t)L_ * B_ * RR * 64);

    int* ent_counts  = iw;                        // NN (becomes cursor)
    int* ent_rowptr  = ent_counts + NN;           // NN+1
    int* ent_bsums   = ent_rowptr + NN + 1;       // 32
    int* ent_packed  = ent_bsums + 32;            // EE
    int* rel_counts  = ent_packed + EE;           // RR (becomes cursor)
    int* rel_rowptr  = rel_counts + RR;           // RR+1
    int* rel_bsums   = rel_rowptr + RR + 1;       // 8
    int* rel_packed  = rel_bsums + 8;             // ER_

    const int ENT_NB = (NN + 1023) / 1024;        // 20
    const int REL_NB = (RR + 1023) / 1024;        // 1

    // ---- CSR build (both graphs, 6 dispatches) ----
    k_zero2<<<(NN + RR + 255) / 256, 256, 0, stream>>>(ent_counts, rel_counts);
    k_hist2<<<(EE + ER_ + 255) / 256, 256, 0, stream>>>(edge_index, rel_ei, ent_counts, rel_counts);
    k_scan1_2<<<ENT_NB + REL_NB, 256, 0, stream>>>(ent_counts, ent_rowptr, ent_bsums,
                                                   rel_counts, rel_rowptr, rel_bsums, ENT_NB);
    k_scan2_2<<<1, 64, 0, stream>>>(ent_bsums, ENT_NB, ent_rowptr + NN,
                                    rel_bsums, REL_NB, rel_rowptr + RR);
    k_scan3_2<<<(NN + RR + 255) / 256, 256, 0, stream>>>(ent_rowptr, ent_bsums, ent_counts,
                                                         rel_rowptr, rel_bsums, rel_counts);
    k_fill2<<<(EE + ER_ + 255) / 256, 256, 0, stream>>>(edge_index, edge_type, rel_ei, rel_et,
                                                        ent_counts, rel_counts, ent_packed, rel_packed);

    // ---- relation-graph model (fused layers, double-buffered) ----
    float* rf[2] = {rel_buf0, rel_buf1};
    const int RTILES = (RR + 3) / 4;              // 50
    k_layer10<RR, 0, true><<<RTILES, 256, 0, stream>>>(
        nullptr, rf[0], nullptr, nullptr, rel_emb,
        rel_rowptr, rel_packed, nullptr, batch,
        Wr, br, gr, btr, RTILES);
    int rc = 0;
    for (int l = 1; l < L_; ++l) {
        k_layer10<RR, 0, false><<<RTILES, 256, 0, stream>>>(
            rf[rc], rf[rc ^ 1], nullptr, nullptr, rel_emb,
            rel_rowptr, rel_packed, nullptr, batch,
            Wr + l * 8192, br + l * 64, gr + l * 64, btr + l * 64, RTILES);
        rc ^= 1;
    }
    float* rel_final = rf[rc];

    // ---- entity-graph model ----
    k_query<<<1, 256, 0, stream>>>(rel_final, batch, query);
    k_rel_mlp_all<<<L_ * B_ * RR, 64, 0, stream>>>(rel_final, Wp1, bp1, Wp2, bp2, rel_all);
    float* xf[2] = {x0, x1};
    u16*   xh[2] = {xb0, xb1};
    const int ETILES = (NN + 3) / 4;              // 5000
    const int EGRID  = 1536;                      // 6 blocks/CU x 256 CU
    k_layer10<NN, 1, true><<<EGRID, 256, 0, stream>>>(
        nullptr, xf[0], nullptr, xh[0], rel_all,
        ent_rowptr, ent_packed, query, batch,
        We, be, ge, bte, ETILES);
    int ec = 0;
    for (int l = 1; l < L_; ++l) {
        k_layer10<NN, 1, false><<<EGRID, 256, 0, stream>>>(
            xf[ec], xf[ec ^ 1], xh[ec], xh[ec ^ 1],
            rel_all + (size_t)l * B_ * RR * 64,
            ent_rowptr, ent_packed, query, batch,
            We + l * 8192, be + l * 64, ge + l * 64, bte + l * 64, ETILES);
        ec ^= 1;
    }
    k_final<<<B_ * K_, 128, 0, stream>>>(xf[ec], query, batch, W1, b1, W2, b2,
                                         (float*)d_out);
}

// Round 17
// 527.940 us; speedup vs baseline: 1.3108x; 1.3108x over previous
//
#include <hip/hip_runtime.h>
#include <hip/hip_bf16.h>

#define D_   64
#define L_   6
#define B_   4
#define K_   256
#define NN   20000
#define EE   200000
#define RR   200
#define ER_  4000
#define EPS_ 1e-5f

typedef unsigned short u16;
typedef unsigned int   u32;
typedef short bf16x8 __attribute__((ext_vector_type(8)));
typedef float f32x4  __attribute__((ext_vector_type(4)));

__device__ __forceinline__ u16 f2bf(float f) {          // RNE f32 -> bf16
    u32 u = __float_as_uint(f);
    u += 0x7FFF + ((u >> 16) & 1);
    return (u16)(u >> 16);
}
__device__ __forceinline__ u32 pack2bf(float a, float b) {
    return (u32)f2bf(a) | ((u32)f2bf(b) << 16);
}
__device__ __forceinline__ float bflo(u32 u) { return __uint_as_float(u << 16); }
__device__ __forceinline__ float bfhi(u32 u) { return __uint_as_float(u & 0xFFFF0000u); }

// ================= CSR build (both graphs per dispatch) =================
__global__ __launch_bounds__(256)
void k_zero2(int* __restrict__ ec, int* __restrict__ rc) {
    int i = blockIdx.x * 256 + threadIdx.x;
    if (i < NN) ec[i] = 0;
    else if (i < NN + RR) rc[i - NN] = 0;
}

__global__ __launch_bounds__(256)
void k_hist2(const int* __restrict__ ei, const int* __restrict__ rei,
             int* __restrict__ ec, int* __restrict__ rc) {
    int g = blockIdx.x * 256 + threadIdx.x;
    if (g < EE) atomicAdd(&ec[ei[EE + g]], 1);
    else if (g < EE + ER_) atomicAdd(&rc[rei[ER_ + (g - EE)]], 1);
}

__global__ __launch_bounds__(256)
void k_scan1_2(const int* __restrict__ e_counts, int* __restrict__ e_pre, int* __restrict__ e_bs,
               const int* __restrict__ r_counts, int* __restrict__ r_pre, int* __restrict__ r_bs,
               int ent_nb) {
    __shared__ int tsum[256];
    const int* counts; int* pre; int* bs; int n; int blk;
    if ((int)blockIdx.x < ent_nb) { counts = e_counts; pre = e_pre; bs = e_bs; n = NN; blk = blockIdx.x; }
    else                          { counts = r_counts; pre = r_pre; bs = r_bs; n = RR; blk = 0; }
    int tid = threadIdx.x;
    int base = blk * 1024 + tid * 4;
    int c0 = 0, c1 = 0, c2 = 0, c3 = 0;
    if (base + 0 < n) c0 = counts[base + 0];
    if (base + 1 < n) c1 = counts[base + 1];
    if (base + 2 < n) c2 = counts[base + 2];
    if (base + 3 < n) c3 = counts[base + 3];
    tsum[tid] = c0 + c1 + c2 + c3;
    __syncthreads();
    if (tid == 0) {
        int acc = 0;
        for (int i = 0; i < 256; i++) { int t = tsum[i]; tsum[i] = acc; acc += t; }
    }
    __syncthreads();
    int run = tsum[tid];
    if (base + 0 < n) pre[base + 0] = run; run += c0;
    if (base + 1 < n) pre[base + 1] = run; run += c1;
    if (base + 2 < n) pre[base + 2] = run; run += c2;
    if (base + 3 < n) pre[base + 3] = run; run += c3;
    if (tid == 255) bs[blk] = run;
}

__global__ __launch_bounds__(64)
void k_scan2_2(int* __restrict__ eb, int enb, int* __restrict__ etot,
               int* __restrict__ rb, int rnb, int* __restrict__ rtot) {
    if (threadIdx.x == 0) {
        int acc = 0;
        for (int i = 0; i < enb; i++) { int t = eb[i]; eb[i] = acc; acc += t; }
        *etot = acc;
    }
    if (threadIdx.x == 1) {
        int acc = 0;
        for (int i = 0; i < rnb; i++) { int t = rb[i]; rb[i] = acc; acc += t; }
        *rtot = acc;
    }
}

__global__ __launch_bounds__(256)
void k_scan3_2(int* __restrict__ e_rp, const int* __restrict__ e_bs, int* __restrict__ e_cur,
               int* __restrict__ r_rp, const int* __restrict__ r_bs, int* __restrict__ r_cur) {
    int i = blockIdx.x * 256 + threadIdx.x;
    if (i < NN) {
        int v = e_rp[i] + e_bs[i >> 10];
        e_rp[i] = v; e_cur[i] = v;
    } else if (i < NN + RR) {
        int j = i - NN;
        int v = r_rp[j] + r_bs[j >> 10];
        r_rp[j] = v; r_cur[j] = v;
    }
}

__global__ __launch_bounds__(256)
void k_fill2(const int* __restrict__ ei, const int* __restrict__ et,
             const int* __restrict__ rei, const int* __restrict__ ret,
             int* __restrict__ e_cur, int* __restrict__ r_cur,
             int* __restrict__ e_packed, int* __restrict__ r_packed) {
    int g = blockIdx.x * 256 + threadIdx.x;
    if (g < EE) {
        int pos = atomicAdd(&e_cur[ei[EE + g]], 1);
        e_packed[pos] = ei[g] | (et[g] << 15);
    } else if (g < EE + ER_) {
        int h = g - EE;
        int pos = atomicAdd(&r_cur[rei[ER_ + h]], 1);
        r_packed[pos] = rei[h] | (ret[h] << 15);
    }
}

// ========== fused layer v10b: persistent blocks, W staged once, NO reg cap ==
template<int NNODES, int MODE, bool FIRST>
__global__ __launch_bounds__(256)
void k_layer10(const float* __restrict__ xin, float* __restrict__ xout,
               const u16* __restrict__ xbin, u16* __restrict__ xbout,
               const void* __restrict__ relv,
               const int* __restrict__ rowptr, const int* __restrict__ packed,
               const float* __restrict__ query, const int* __restrict__ batch,
               const float* __restrict__ W, const float* __restrict__ bias,
               const float* __restrict__ gw, const float* __restrict__ bt,
               int ntiles) {
    __shared__ u16 Wt[2][64][72];    // both W halves, transposed [n][k], bf16
    __shared__ u16 As[16][72];       // message tile (bf16)
    __shared__ u16 Xs[16][72];       // x tile (bf16)
    __shared__ float LNbuf[16][65];  // f32 GEMM out for cross-wave LN
    const int tid   = threadIdx.x;
    const int lane  = tid & 63;
    const int wv    = tid >> 6;      // 0..3

    int bn0 = batch[0 * K_ * 3 + (MODE ? 0 : 2)];
    int bn1 = batch[1 * K_ * 3 + (MODE ? 0 : 2)];
    int bn2 = batch[2 * K_ * 3 + (MODE ? 0 : 2)];
    int bn3 = batch[3 * K_ * 3 + (MODE ? 0 : 2)];

    // ---- stage BOTH W halves (transposed + bf16), once per block ----
    #pragma unroll
    for (int half = 0; half < 2; half++) {
        int n = lane, k16 = wv * 16;
        u32 buf[8];
        #pragma unroll
        for (int j2 = 0; j2 < 8; j2++) {
            float w0 = W[(half * 64 + k16 + 2 * j2    ) * 64 + n];
            float w1 = W[(half * 64 + k16 + 2 * j2 + 1) * 64 + n];
            buf[j2] = pack2bf(w0, w1);
        }
        uint4* dst = reinterpret_cast<uint4*>(&Wt[half][n][k16]);
        dst[0] = make_uint4(buf[0], buf[1], buf[2], buf[3]);
        dst[1] = make_uint4(buf[4], buf[5], buf[6], buf[7]);
    }

    float qreg[4][8];
    const int slot = lane >> 3;   // edge slot 0..7
    const int d8   = lane & 7;    // 8-dim block
    if constexpr (MODE == 1) {
        #pragma unroll
        for (int b = 0; b < 4; b++) {
            float4 q0 = *reinterpret_cast<const float4*>(query + b * 64 + d8 * 8);
            float4 q1 = *reinterpret_cast<const float4*>(query + b * 64 + d8 * 8 + 4);
            qreg[b][0]=q0.x; qreg[b][1]=q0.y; qreg[b][2]=q0.z; qreg[b][3]=q0.w;
            qreg[b][4]=q1.x; qreg[b][5]=q1.y; qreg[b][6]=q1.z; qreg[b][7]=q1.w;
        }
    }

    const int erow = wv * 4 + (lane >> 4);   // 0..15 epilogue row
    const int tx   = lane & 15;
    const int al   = lane & 15;
    const int ag   = lane >> 4;

    for (int tile = blockIdx.x; tile < ntiles; tile += gridDim.x) {
        const int node0 = tile * 4;

        // ---- prefetch rowptr + f32 residual (overlap with staging/gather) --
        const int gnode = node0 + wv;
        int beg = 0, end = 0;
        if (gnode < NNODES) { beg = rowptr[gnode]; end = rowptr[gnode + 1]; }

        float4 resf = make_float4(0.f, 0.f, 0.f, 0.f);
        if constexpr (!FIRST) {
            int b = erow >> 2, nd = node0 + (erow & 3);
            if (nd < NNODES)
                resf = *reinterpret_cast<const float4*>(
                    xin + ((size_t)b * NNODES + nd) * 64 + tx * 4);
        }

        // ---- stage Xs <- x state (or implicit boundary): 128 items ----
        if (tid < 128) {
            int m = tid >> 3, o8 = (tid & 7) * 8;
            int b = m >> 2, node = node0 + (m & 3);
            uint4 v = make_uint4(0, 0, 0, 0);
            if (node < NNODES) {
                if constexpr (FIRST) {
                    int bnb = (b==0)?bn0:(b==1)?bn1:(b==2)?bn2:bn3;
                    if (node == bnb) {
                        if constexpr (MODE == 1) {
                            const float* q = query + b * 64 + o8;
                            v = make_uint4(pack2bf(q[0], q[1]), pack2bf(q[2], q[3]),
                                           pack2bf(q[4], q[5]), pack2bf(q[6], q[7]));
                        } else {
                            v = make_uint4(0x3F803F80u, 0x3F803F80u, 0x3F803F80u, 0x3F803F80u);
                        }
                    }
                } else if constexpr (MODE == 1) {
                    v = *reinterpret_cast<const uint4*>(
                        xbin + ((size_t)b * NNODES + node) * 64 + o8);
                } else {
                    const float* src = xin + ((size_t)b * NNODES + node) * 64 + o8;
                    float4 x0 = *reinterpret_cast<const float4*>(src);
                    float4 x1 = *reinterpret_cast<const float4*>(src + 4);
                    v = make_uint4(pack2bf(x0.x, x0.y), pack2bf(x0.z, x0.w),
                                   pack2bf(x1.x, x1.y), pack2bf(x1.z, x1.w));
                }
            }
            *reinterpret_cast<uint4*>(&Xs[m][o8]) = v;
        }

        // ---- gather: wave wv handles node gnode ----
        {
            float acc[4][8];
            #pragma unroll
            for (int b = 0; b < 4; b++)
                #pragma unroll
                for (int i = 0; i < 8; i++) acc[b][i] = 0.f;

            for (int e0 = beg; e0 < end; e0 += 16) {
                #pragma unroll
                for (int half = 0; half < 2; half++) {
                    int e = e0 + half * 8 + slot;
                    if (e < end) {
                        int p = packed[e];
                        int src = p & 0x7FFF;
                        int et  = p >> 15;
                        if constexpr (MODE == 1) {
                            const u16* rb = (const u16*)relv;
                            if constexpr (FIRST) {
                                #pragma unroll
                                for (int b = 0; b < 4; b++) {
                                    int bnb = (b==0)?bn0:(b==1)?bn1:(b==2)?bn2:bn3;
                                    if (src == bnb) {
                                        uint4 rv = *reinterpret_cast<const uint4*>(
                                            rb + ((size_t)(b * RR + et)) * 64 + d8 * 8);
                                        acc[b][0] = fmaf(qreg[b][0], bflo(rv.x), acc[b][0]);
                                        acc[b][1] = fmaf(qreg[b][1], bfhi(rv.x), acc[b][1]);
                                        acc[b][2] = fmaf(qreg[b][2], bflo(rv.y), acc[b][2]);
                                        acc[b][3] = fmaf(qreg[b][3], bfhi(rv.y), acc[b][3]);
                                        acc[b][4] = fmaf(qreg[b][4], bflo(rv.z), acc[b][4]);
                                        acc[b][5] = fmaf(qreg[b][5], bfhi(rv.z), acc[b][5]);
                                        acc[b][6] = fmaf(qreg[b][6], bflo(rv.w), acc[b][6]);
                                        acc[b][7] = fmaf(qreg[b][7], bfhi(rv.w), acc[b][7]);
                                    }
                                }
                            } else {
                                #pragma unroll
                                for (int b = 0; b < 4; b++) {
                                    uint4 xv = *reinterpret_cast<const uint4*>(
                                        xbin + ((size_t)(b * NNODES + src)) * 64 + d8 * 8);
                                    uint4 rv = *reinterpret_cast<const uint4*>(
                                        ((const u16*)relv) + ((size_t)(b * RR + et)) * 64 + d8 * 8);
                                    acc[b][0] = fmaf(bflo(xv.x), bflo(rv.x), acc[b][0]);
                                    acc[b][1] = fmaf(bfhi(xv.x), bfhi(rv.x), acc[b][1]);
                                    acc[b][2] = fmaf(bflo(xv.y), bflo(rv.y), acc[b][2]);
                                    acc[b][3] = fmaf(bfhi(xv.y), bfhi(rv.y), acc[b][3]);
                                    acc[b][4] = fmaf(bflo(xv.z), bflo(rv.z), acc[b][4]);
                                    acc[b][5] = fmaf(bfhi(xv.z), bfhi(rv.z), acc[b][5]);
                                    acc[b][6] = fmaf(bflo(xv.w), bflo(rv.w), acc[b][6]);
                                    acc[b][7] = fmaf(bfhi(xv.w), bfhi(rv.w), acc[b][7]);
                                }
                            }
                        } else {
                            const float* re = (const float*)relv;
                            if constexpr (FIRST) {
                                bool m0 = (src == bn0), m1 = (src == bn1),
                                     m2 = (src == bn2), m3 = (src == bn3);
                                if (m0 | m1 | m2 | m3) {
                                    float4 r0 = *reinterpret_cast<const float4*>(re + et * 64 + d8 * 8);
                                    float4 r1 = *reinterpret_cast<const float4*>(re + et * 64 + d8 * 8 + 4);
                                    float rr[8] = {r0.x,r0.y,r0.z,r0.w,r1.x,r1.y,r1.z,r1.w};
                                    if (m0) {
                                        #pragma unroll
                                        for (int i = 0; i < 8; i++) acc[0][i] += rr[i];
                                    }
                                    if (m1) {
                                        #pragma unroll
                                        for (int i = 0; i < 8; i++) acc[1][i] += rr[i];
                                    }
                                    if (m2) {
                                        #pragma unroll
                                        for (int i = 0; i < 8; i++) acc[2][i] += rr[i];
                                    }
                                    if (m3) {
                                        #pragma unroll
                                        for (int i = 0; i < 8; i++) acc[3][i] += rr[i];
                                    }
                                }
                            } else {
                                float4 r0 = *reinterpret_cast<const float4*>(re + et * 64 + d8 * 8);
                                float4 r1 = *reinterpret_cast<const float4*>(re + et * 64 + d8 * 8 + 4);
                                #pragma unroll
                                for (int b = 0; b < 4; b++) {
                                    const float* xr = xin + ((size_t)(b * NNODES + src)) * 64 + d8 * 8;
                                    float4 x0 = *reinterpret_cast<const float4*>(xr);
                                    float4 x1 = *reinterpret_cast<const float4*>(xr + 4);
                                    acc[b][0] = fmaf(x0.x, r0.x, acc[b][0]);
                                    acc[b][1] = fmaf(x0.y, r0.y, acc[b][1]);
                                    acc[b][2] = fmaf(x0.z, r0.z, acc[b][2]);
                                    acc[b][3] = fmaf(x0.w, r0.w, acc[b][3]);
                                    acc[b][4] = fmaf(x1.x, r1.x, acc[b][4]);
                                    acc[b][5] = fmaf(x1.y, r1.y, acc[b][5]);
                                    acc[b][6] = fmaf(x1.z, r1.z, acc[b][6]);
                                    acc[b][7] = fmaf(x1.w, r1.w, acc[b][7]);
                                }
                            }
                        }
                    }
                }
            }

            #pragma unroll
            for (int b = 0; b < 4; b++)
                #pragma unroll
                for (int i = 0; i < 8; i++) {
                    float v = acc[b][i];
                    v += __shfl_xor(v, 8);
                    v += __shfl_xor(v, 16);
                    v += __shfl_xor(v, 32);
                    acc[b][i] = v;
                }

            if (slot < 4) {
                float out[8];
                #pragma unroll
                for (int i = 0; i < 8; i++)
                    out[i] = (slot==0) ? acc[0][i] : (slot==1) ? acc[1][i]
                           : (slot==2) ? acc[2][i] : acc[3][i];
                int bnb = (slot==0)?bn0:(slot==1)?bn1:(slot==2)?bn2:bn3;
                if (gnode < NNODES && gnode == bnb) {
                    if constexpr (MODE == 1) {
                        #pragma unroll
                        for (int i = 0; i < 8; i++)
                            out[i] += (slot==0)?qreg[0][i]:(slot==1)?qreg[1][i]
                                     :(slot==2)?qreg[2][i]:qreg[3][i];
                    } else {
                        #pragma unroll
                        for (int i = 0; i < 8; i++) out[i] += 1.0f;
                    }
                }
                int m = slot * 4 + wv;
                *reinterpret_cast<uint4*>(&As[m][d8 * 8]) =
                    make_uint4(pack2bf(out[0], out[1]), pack2bf(out[2], out[3]),
                               pack2bf(out[4], out[5]), pack2bf(out[6], out[7]));
            }
        }
        __syncthreads();

        // ---- MFMA: both passes back-to-back (wave = n-tile) ----
        const int nt = wv;
        f32x4 acc4 = (f32x4){0.f, 0.f, 0.f, 0.f};
        {
            bf16x8 a0 = *reinterpret_cast<const bf16x8*>(&As[al][ag * 8]);
            bf16x8 a1 = *reinterpret_cast<const bf16x8*>(&As[al][32 + ag * 8]);
            bf16x8 b0 = *reinterpret_cast<const bf16x8*>(&Wt[1][nt * 16 + al][ag * 8]);
            bf16x8 b1 = *reinterpret_cast<const bf16x8*>(&Wt[1][nt * 16 + al][32 + ag * 8]);
            acc4 = __builtin_amdgcn_mfma_f32_16x16x32_bf16(a0, b0, acc4, 0, 0, 0);
            acc4 = __builtin_amdgcn_mfma_f32_16x16x32_bf16(a1, b1, acc4, 0, 0, 0);
            bf16x8 x0 = *reinterpret_cast<const bf16x8*>(&Xs[al][ag * 8]);
            bf16x8 x1 = *reinterpret_cast<const bf16x8*>(&Xs[al][32 + ag * 8]);
            bf16x8 d0 = *reinterpret_cast<const bf16x8*>(&Wt[0][nt * 16 + al][ag * 8]);
            bf16x8 d1 = *reinterpret_cast<const bf16x8*>(&Wt[0][nt * 16 + al][32 + ag * 8]);
            acc4 = __builtin_amdgcn_mfma_f32_16x16x32_bf16(x0, d0, acc4, 0, 0, 0);
            acc4 = __builtin_amdgcn_mfma_f32_16x16x32_bf16(x1, d1, acc4, 0, 0, 0);
        }
        #pragma unroll
        for (int reg = 0; reg < 4; reg++)
            LNbuf[ag * 4 + reg][nt * 16 + al] = acc4[reg];
        __syncthreads();

        // ---- epilogue: wave wv handles rows wv*4..wv*4+3 ----
        {
            int row = erow;
            int b = row >> 2, node = node0 + (row & 3);
            float o[4];
            float s1 = 0.f, s2 = 0.f;
            #pragma unroll
            for (int i = 0; i < 4; i++) {
                o[i] = LNbuf[row][tx * 4 + i] + bias[tx * 4 + i];
                s1 += o[i];
                s2 += o[i] * o[i];
            }
            s1 += __shfl_xor(s1, 1); s2 += __shfl_xor(s2, 1);
            s1 += __shfl_xor(s1, 2); s2 += __shfl_xor(s2, 2);
            s1 += __shfl_xor(s1, 4); s2 += __shfl_xor(s2, 4);
            s1 += __shfl_xor(s1, 8); s2 += __shfl_xor(s2, 8);
            float mean = s1 * (1.f / 64.f);
            float var  = s2 * (1.f / 64.f) - mean * mean;
            float inv  = rsqrtf(var + EPS_);
            if (node < NNODES) {
                int bnb = (b==0)?bn0:(b==1)?bn1:(b==2)?bn2:bn3;
                size_t ro = ((size_t)b * NNODES + node) * 64;
                float r[4] = {resf.x, resf.y, resf.z, resf.w};
                if constexpr (FIRST) {
                    r[0] = r[1] = r[2] = r[3] = 0.f;
                    if (node == bnb) {
                        if constexpr (MODE == 1) {
                            float4 q = *reinterpret_cast<const float4*>(query + b * 64 + tx * 4);
                            r[0] = q.x; r[1] = q.y; r[2] = q.z; r[3] = q.w;
                        } else {
                            r[0] = r[1] = r[2] = r[3] = 1.0f;
                        }
                    }
                }
                float nv[4];
                #pragma unroll
                for (int i = 0; i < 4; i++) {
                    float h = (o[i] - mean) * inv * gw[tx * 4 + i] + bt[tx * 4 + i];
                    h = fmaxf(h, 0.f);
                    nv[i] = r[i] + h;
                }
                *reinterpret_cast<float4*>(&xout[ro + tx * 4]) =
                    make_float4(nv[0], nv[1], nv[2], nv[3]);
                if constexpr (MODE == 1) {
                    ushort4 b4;
                    b4.x = f2bf(nv[0]); b4.y = f2bf(nv[1]);
                    b4.z = f2bf(nv[2]); b4.w = f2bf(nv[3]);
                    *reinterpret_cast<ushort4*>(&xbout[ro + tx * 4]) = b4;
                }
            }
        }
    }
}

// ========== all-layer relation MLP: rel_all[l] = relu(rel_repr@Wp1+b)@Wp2+b (bf16)
__global__ __launch_bounds__(64)
void k_rel_mlp_all(const float* __restrict__ rel_repr,
                   const float* __restrict__ Wp1, const float* __restrict__ bp1,
                   const float* __restrict__ Wp2, const float* __restrict__ bp2,
                   u16* __restrict__ out) {
    __shared__ float rowv[64];
    __shared__ float hid[64];
    int l     = blockIdx.x / (B_ * RR);
    int rowid = blockIdx.x % (B_ * RR);
    int d = threadIdx.x;
    const float* w1 = Wp1 + l * 4096;
    const float* w2 = Wp2 + l * 4096;
    rowv[d] = rel_repr[rowid * 64 + d];
    __syncthreads();
    float acc = bp1[l * 64 + d];
    for (int k = 0; k < 64; k++) acc = fmaf(rowv[k], w1[k * 64 + d], acc);
    hid[d] = fmaxf(acc, 0.f);
    __syncthreads();
    float o = bp2[l * 64 + d];
    for (int k = 0; k < 64; k++) o = fmaf(hid[k], w2[k * 64 + d], o);
    out[(size_t)l * B_ * RR * 64 + rowid * 64 + d] = f2bf(o);
}

// ================= query[b] = rel_repr[b, r_index[b]] ======================
__global__ __launch_bounds__(256)
void k_query(const float* __restrict__ rel_repr, const int* __restrict__ batch,
             float* __restrict__ query) {
    int tid = threadIdx.x;  // 256 = B*64
    int b = tid >> 6;
    int d = tid & 63;
    int r = batch[b * K_ * 3 + 2];
    query[b * 64 + d] = rel_repr[(b * RR + r) * 64 + d];
}

// ================= final MLP over gathered rows ============================
__global__ __launch_bounds__(128)
void k_final(const float* __restrict__ x, const float* __restrict__ query,
             const int* __restrict__ batch,
             const float* __restrict__ W1, const float* __restrict__ b1,
             const float* __restrict__ W2, const float* __restrict__ b2,
             float* __restrict__ out) {
    __shared__ float feat[128];
    __shared__ float partial[2];
    int pair = blockIdx.x;          // b*K + k
    int b = pair / K_;
    int t = batch[pair * 3 + 1];
    int d = threadIdx.x;
    feat[d] = (d < 64) ? x[(size_t)(b * NN + t) * 64 + d] : query[b * 64 + (d - 64)];
    __syncthreads();
    float h = b1[d];
    for (int i = 0; i < 128; i++) h = fmaf(feat[i], W1[i * 128 + d], h);
    h = fmaxf(h, 0.f);
    float v = h * W2[d];
    #pragma unroll
    for (int off = 1; off < 64; off <<= 1) v += __shfl_xor(v, off);
    if ((d & 63) == 0) partial[d >> 6] = v;
    __syncthreads();
    if (d == 0) out[pair] = partial[0] + partial[1] + b2[0];
}

extern "C" void kernel_launch(void* const* d_in, const int* in_sizes, int n_in,
                              void* d_out, int out_size, void* d_ws, size_t ws_size,
                              hipStream_t stream) {
    const int* batch      = (const int*)d_in[0];
    const int* edge_index = (const int*)d_in[1];
    const int* edge_type  = (const int*)d_in[2];
    const int* rel_ei     = (const int*)d_in[3];
    const int* rel_et     = (const int*)d_in[4];
    const float* rel_emb = (const float*)d_in[7];
    const float* Wr  = (const float*)d_in[8];
    const float* br  = (const float*)d_in[9];
    const float* gr  = (const float*)d_in[10];
    const float* btr = (const float*)d_in[11];
    const float* Wp1 = (const float*)d_in[12];
    const float* bp1 = (const float*)d_in[13];
    const float* Wp2 = (const float*)d_in[14];
    const float* bp2 = (const float*)d_in[15];
    const float* We  = (const float*)d_in[16];
    const float* be  = (const float*)d_in[17];
    const float* ge  = (const float*)d_in[18];
    const float* bte = (const float*)d_in[19];
    const float* W1  = (const float*)d_in[20];
    const float* b1  = (const float*)d_in[21];
    const float* W2  = (const float*)d_in[22];
    const float* b2  = (const float*)d_in[23];

    float* ws = (float*)d_ws;
    float* rel_buf0 = ws;                              // 51200
    float* rel_buf1 = rel_buf0 + 51200;                // 51200
    float* query    = rel_buf1 + 51200;                // 256
    float* x0       = query + 256;                     // 5,120,000
    float* x1       = x0 + (size_t)B_ * NN * 64;       // 5,120,000
    u16*   xb0      = (u16*)(x1 + (size_t)B_ * NN * 64);          // 5.12M u16
    u16*   xb1      = xb0 + (size_t)B_ * NN * 64;                 // 5.12M u16
    u16*   rel_all  = xb1 + (size_t)B_ * NN * 64;                 // L*B*RR*64 u16
    int*   iw       = (int*)(rel_all + (size_t)L_ * B_ * RR * 64);

    int* ent_counts  = iw;                        // NN (becomes cursor)
    int* ent_rowptr  = ent_counts + NN;           // NN+1
    int* ent_bsums   = ent_rowptr + NN + 1;       // 32
    int* ent_packed  = ent_bsums + 32;            // EE
    int* rel_counts  = ent_packed + EE;           // RR (becomes cursor)
    int* rel_rowptr  = rel_counts + RR;           // RR+1
    int* rel_bsums   = rel_rowptr + RR + 1;       // 8
    int* rel_packed  = rel_bsums + 8;             // ER_

    const int ENT_NB = (NN + 1023) / 1024;        // 20
    const int REL_NB = (RR + 1023) / 1024;        // 1

    // ---- CSR build (both graphs, 6 dispatches) ----
    k_zero2<<<(NN + RR + 255) / 256, 256, 0, stream>>>(ent_counts, rel_counts);
    k_hist2<<<(EE + ER_ + 255) / 256, 256, 0, stream>>>(edge_index, rel_ei, ent_counts, rel_counts);
    k_scan1_2<<<ENT_NB + REL_NB, 256, 0, stream>>>(ent_counts, ent_rowptr, ent_bsums,
                                                   rel_counts, rel_rowptr, rel_bsums, ENT_NB);
    k_scan2_2<<<1, 64, 0, stream>>>(ent_bsums, ENT_NB, ent_rowptr + NN,
                                    rel_bsums, REL_NB, rel_rowptr + RR);
    k_scan3_2<<<(NN + RR + 255) / 256, 256, 0, stream>>>(ent_rowptr, ent_bsums, ent_counts,
                                                         rel_rowptr, rel_bsums, rel_counts);
    k_fill2<<<(EE + ER_ + 255) / 256, 256, 0, stream>>>(edge_index, edge_type, rel_ei, rel_et,
                                                        ent_counts, rel_counts, ent_packed, rel_packed);

    // ---- relation-graph model (fused layers, double-buffered) ----
    float* rf[2] = {rel_buf0, rel_buf1};
    const int RTILES = (RR + 3) / 4;              // 50
    k_layer10<RR, 0, true><<<RTILES, 256, 0, stream>>>(
        nullptr, rf[0], nullptr, nullptr, rel_emb,
        rel_rowptr, rel_packed, nullptr, batch,
        Wr, br, gr, btr, RTILES);
    int rc = 0;
    for (int l = 1; l < L_; ++l) {
        k_layer10<RR, 0, false><<<RTILES, 256, 0, stream>>>(
            rf[rc], rf[rc ^ 1], nullptr, nullptr, rel_emb,
            rel_rowptr, rel_packed, nullptr, batch,
            Wr + l * 8192, br + l * 64, gr + l * 64, btr + l * 64, RTILES);
        rc ^= 1;
    }
    float* rel_final = rf[rc];

    // ---- entity-graph model ----
    k_query<<<1, 256, 0, stream>>>(rel_final, batch, query);
    k_rel_mlp_all<<<L_ * B_ * RR, 64, 0, stream>>>(rel_final, Wp1, bp1, Wp2, bp2, rel_all);
    float* xf[2] = {x0, x1};
    u16*   xh[2] = {xb0, xb1};
    const int ETILES = (NN + 3) / 4;              // 5000
    const int EGRID  = 1280;                      // 5 blocks/CU x 256 CU
    k_layer10<NN, 1, true><<<EGRID, 256, 0, stream>>>(
        nullptr, xf[0], nullptr, xh[0], rel_all,
        ent_rowptr, ent_packed, query, batch,
        We, be, ge, bte, ETILES);
    int ec = 0;
    for (int l = 1; l < L_; ++l) {
        k_layer10<NN, 1, false><<<EGRID, 256, 0, stream>>>(
            xf[ec], xf[ec ^ 1], xh[ec], xh[ec ^ 1],
            rel_all + (size_t)l * B_ * RR * 64,
            ent_rowptr, ent_packed, query, batch,
            We + l * 8192, be + l * 64, ge + l * 64, bte + l * 64, ETILES);
        ec ^= 1;
    }
    k_final<<<B_ * K_, 128, 0, stream>>>(xf[ec], query, batch, W1, b1, W2, b2,
                                         (float*)d_out);
}

// Round 18
// 400.204 us; speedup vs baseline: 1.7292x; 1.3192x over previous
//
#include <hip/hip_runtime.h>
#include <hip/hip_bf16.h>

#define D_   64
#define L_   6
#define B_   4
#define K_   256
#define NN   20000
#define EE   200000
#define RR   200
#define ER_  4000
#define EPS_ 1e-5f

typedef unsigned short u16;
typedef unsigned int   u32;
typedef short bf16x8 __attribute__((ext_vector_type(8)));
typedef float f32x4  __attribute__((ext_vector_type(4)));

__device__ __forceinline__ u16 f2bf(float f) {          // RNE f32 -> bf16
    u32 u = __float_as_uint(f);
    u += 0x7FFF + ((u >> 16) & 1);
    return (u16)(u >> 16);
}
__device__ __forceinline__ u32 pack2bf(float a, float b) {
    return (u32)f2bf(a) | ((u32)f2bf(b) << 16);
}
__device__ __forceinline__ float bflo(u32 u) { return __uint_as_float(u << 16); }
__device__ __forceinline__ float bfhi(u32 u) { return __uint_as_float(u & 0xFFFF0000u); }

// ================= CSR build (both graphs per dispatch) =================
__global__ __launch_bounds__(256)
void k_zero2(int* __restrict__ ec, int* __restrict__ rc) {
    int i = blockIdx.x * 256 + threadIdx.x;
    if (i < NN) ec[i] = 0;
    else if (i < NN + RR) rc[i - NN] = 0;
}

__global__ __launch_bounds__(256)
void k_hist2(const int* __restrict__ ei, const int* __restrict__ rei,
             int* __restrict__ ec, int* __restrict__ rc) {
    int g = blockIdx.x * 256 + threadIdx.x;
    if (g < EE) atomicAdd(&ec[ei[EE + g]], 1);
    else if (g < EE + ER_) atomicAdd(&rc[rei[ER_ + (g - EE)]], 1);
}

__global__ __launch_bounds__(256)
void k_scan1_2(const int* __restrict__ e_counts, int* __restrict__ e_pre, int* __restrict__ e_bs,
               const int* __restrict__ r_counts, int* __restrict__ r_pre, int* __restrict__ r_bs,
               int ent_nb) {
    __shared__ int tsum[256];
    const int* counts; int* pre; int* bs; int n; int blk;
    if ((int)blockIdx.x < ent_nb) { counts = e_counts; pre = e_pre; bs = e_bs; n = NN; blk = blockIdx.x; }
    else                          { counts = r_counts; pre = r_pre; bs = r_bs; n = RR; blk = 0; }
    int tid = threadIdx.x;
    int base = blk * 1024 + tid * 4;
    int c0 = 0, c1 = 0, c2 = 0, c3 = 0;
    if (base + 0 < n) c0 = counts[base + 0];
    if (base + 1 < n) c1 = counts[base + 1];
    if (base + 2 < n) c2 = counts[base + 2];
    if (base + 3 < n) c3 = counts[base + 3];
    tsum[tid] = c0 + c1 + c2 + c3;
    __syncthreads();
    if (tid == 0) {
        int acc = 0;
        for (int i = 0; i < 256; i++) { int t = tsum[i]; tsum[i] = acc; acc += t; }
    }
    __syncthreads();
    int run = tsum[tid];
    if (base + 0 < n) pre[base + 0] = run; run += c0;
    if (base + 1 < n) pre[base + 1] = run; run += c1;
    if (base + 2 < n) pre[base + 2] = run; run += c2;
    if (base + 3 < n) pre[base + 3] = run; run += c3;
    if (tid == 255) bs[blk] = run;
}

__global__ __launch_bounds__(64)
void k_scan2_2(int* __restrict__ eb, int enb, int* __restrict__ etot,
               int* __restrict__ rb, int rnb, int* __restrict__ rtot) {
    if (threadIdx.x == 0) {
        int acc = 0;
        for (int i = 0; i < enb; i++) { int t = eb[i]; eb[i] = acc; acc += t; }
        *etot = acc;
    }
    if (threadIdx.x == 1) {
        int acc = 0;
        for (int i = 0; i < rnb; i++) { int t = rb[i]; rb[i] = acc; acc += t; }
        *rtot = acc;
    }
}

__global__ __launch_bounds__(256)
void k_scan3_2(int* __restrict__ e_rp, const int* __restrict__ e_bs, int* __restrict__ e_cur,
               int* __restrict__ r_rp, const int* __restrict__ r_bs, int* __restrict__ r_cur) {
    int i = blockIdx.x * 256 + threadIdx.x;
    if (i < NN) {
        int v = e_rp[i] + e_bs[i >> 10];
        e_rp[i] = v; e_cur[i] = v;
    } else if (i < NN + RR) {
        int j = i - NN;
        int v = r_rp[j] + r_bs[j >> 10];
        r_rp[j] = v; r_cur[j] = v;
    }
}

__global__ __launch_bounds__(256)
void k_fill2(const int* __restrict__ ei, const int* __restrict__ et,
             const int* __restrict__ rei, const int* __restrict__ ret,
             int* __restrict__ e_cur, int* __restrict__ r_cur,
             int* __restrict__ e_packed, int* __restrict__ r_packed) {
    int g = blockIdx.x * 256 + threadIdx.x;
    if (g < EE) {
        int pos = atomicAdd(&e_cur[ei[EE + g]], 1);
        e_packed[pos] = ei[g] | (et[g] << 15);
    } else if (g < EE + ER_) {
        int h = g - EE;
        int pos = atomicAdd(&r_cur[rei[ER_ + h]], 1);
        r_packed[pos] = rei[h] | (ret[h] << 15);
    }
}

// ========== fused layer v9: 256 threads, 4 waves x 4 nodes, balanced ========
// Rows m = b*4 + nl (16 rows). Wave wv gathers node node0+wv -> As.
// W staged ONE HALF at a time (LDS 18.4KB -> 8 blocks/CU). All 4 waves GEMM
// (wave = n-tile, 4 MFMA over both passes) + LNbuf + row-parallel epilogue
// with top-prefetched f32 residual.
template<int NNODES, int MODE, bool FIRST>
__global__ __launch_bounds__(256)
void k_layer9(const float* __restrict__ xin, float* __restrict__ xout,
              const u16* __restrict__ xbin, u16* __restrict__ xbout,
              const void* __restrict__ relv,
              const int* __restrict__ rowptr, const int* __restrict__ packed,
              const float* __restrict__ query, const int* __restrict__ batch,
              const float* __restrict__ W, const float* __restrict__ bias,
              const float* __restrict__ gw, const float* __restrict__ bt) {
    __shared__ u16 Wt[64][72];       // ONE W half, transposed [n][k], bf16
    __shared__ u16 As[16][72];       // message tile (bf16)
    __shared__ u16 Xs[16][72];       // x tile (bf16)
    __shared__ float LNbuf[16][68];  // f32 GEMM out for cross-wave LN
    const int tid   = threadIdx.x;
    const int node0 = blockIdx.x * 4;
    const int lane  = tid & 63;
    const int wv    = tid >> 6;      // 0..3

    int bn0 = batch[0 * K_ * 3 + (MODE ? 0 : 2)];
    int bn1 = batch[1 * K_ * 3 + (MODE ? 0 : 2)];
    int bn2 = batch[2 * K_ * 3 + (MODE ? 0 : 2)];
    int bn3 = batch[3 * K_ * 3 + (MODE ? 0 : 2)];

    // ---- prefetch rowptr for this wave's node ----
    const int gnode = node0 + wv;
    int beg = 0, end = 0;
    if (gnode < NNODES) { beg = rowptr[gnode]; end = rowptr[gnode + 1]; }

    // ---- prefetch f32 residual (epilogue rows known): coalesced float4 ----
    const int erow  = wv * 4 + (lane >> 4);   // 0..15
    const int tx    = lane & 15;
    float4 resf = make_float4(0.f, 0.f, 0.f, 0.f);
    if constexpr (!FIRST) {
        int b = erow >> 2, nd = node0 + (erow & 3);
        if (nd < NNODES)
            resf = *reinterpret_cast<const float4*>(
                xin + ((size_t)b * NNODES + nd) * 64 + tx * 4);
    }

    // ---- stage Wt = W_hi (rows 64..127), transposed + bf16: k-seg = wv ----
    {
        int n = lane, k16 = wv * 16;
        u32 buf[8];
        #pragma unroll
        for (int j2 = 0; j2 < 8; j2++) {
            float w0 = W[(64 + k16 + 2 * j2    ) * 64 + n];
            float w1 = W[(64 + k16 + 2 * j2 + 1) * 64 + n];
            buf[j2] = pack2bf(w0, w1);
        }
        uint4* dst = reinterpret_cast<uint4*>(&Wt[n][k16]);
        dst[0] = make_uint4(buf[0], buf[1], buf[2], buf[3]);
        dst[1] = make_uint4(buf[4], buf[5], buf[6], buf[7]);
    }

    // ---- stage Xs <- x state (or implicit boundary): 128 items ----
    if (tid < 128) {
        int m = tid >> 3, o8 = (tid & 7) * 8;
        int b = m >> 2, node = node0 + (m & 3);
        uint4 v = make_uint4(0, 0, 0, 0);
        if (node < NNODES) {
            if constexpr (FIRST) {
                int bnb = (b==0)?bn0:(b==1)?bn1:(b==2)?bn2:bn3;
                if (node == bnb) {
                    if constexpr (MODE == 1) {
                        const float* q = query + b * 64 + o8;
                        v = make_uint4(pack2bf(q[0], q[1]), pack2bf(q[2], q[3]),
                                       pack2bf(q[4], q[5]), pack2bf(q[6], q[7]));
                    } else {
                        v = make_uint4(0x3F803F80u, 0x3F803F80u, 0x3F803F80u, 0x3F803F80u);
                    }
                }
            } else if constexpr (MODE == 1) {
                v = *reinterpret_cast<const uint4*>(
                    xbin + ((size_t)b * NNODES + node) * 64 + o8);
            } else {
                const float* src = xin + ((size_t)b * NNODES + node) * 64 + o8;
                float4 x0 = *reinterpret_cast<const float4*>(src);
                float4 x1 = *reinterpret_cast<const float4*>(src + 4);
                v = make_uint4(pack2bf(x0.x, x0.y), pack2bf(x0.z, x0.w),
                               pack2bf(x1.x, x1.y), pack2bf(x1.z, x1.w));
            }
        }
        *reinterpret_cast<uint4*>(&Xs[m][o8]) = v;
    }

    // ---- gather: wave wv handles node node0+wv ----
    const int slot = lane >> 3;   // edge slot 0..7
    const int d8   = lane & 7;    // 8-dim block

    float qreg[4][8];
    if constexpr (MODE == 1) {
        #pragma unroll
        for (int b = 0; b < 4; b++) {
            float4 q0 = *reinterpret_cast<const float4*>(query + b * 64 + d8 * 8);
            float4 q1 = *reinterpret_cast<const float4*>(query + b * 64 + d8 * 8 + 4);
            qreg[b][0]=q0.x; qreg[b][1]=q0.y; qreg[b][2]=q0.z; qreg[b][3]=q0.w;
            qreg[b][4]=q1.x; qreg[b][5]=q1.y; qreg[b][6]=q1.z; qreg[b][7]=q1.w;
        }
    }

    {
        float acc[4][8];
        #pragma unroll
        for (int b = 0; b < 4; b++)
            #pragma unroll
            for (int i = 0; i < 8; i++) acc[b][i] = 0.f;

        for (int e0 = beg; e0 < end; e0 += 16) {
            #pragma unroll
            for (int half = 0; half < 2; half++) {
                int e = e0 + half * 8 + slot;
                if (e < end) {
                    int p = packed[e];
                    int src = p & 0x7FFF;
                    int et  = p >> 15;
                    if constexpr (MODE == 1) {
                        const u16* rb = (const u16*)relv;
                        if constexpr (FIRST) {
                            #pragma unroll
                            for (int b = 0; b < 4; b++) {
                                int bnb = (b==0)?bn0:(b==1)?bn1:(b==2)?bn2:bn3;
                                if (src == bnb) {
                                    uint4 rv = *reinterpret_cast<const uint4*>(
                                        rb + ((size_t)(b * RR + et)) * 64 + d8 * 8);
                                    acc[b][0] = fmaf(qreg[b][0], bflo(rv.x), acc[b][0]);
                                    acc[b][1] = fmaf(qreg[b][1], bfhi(rv.x), acc[b][1]);
                                    acc[b][2] = fmaf(qreg[b][2], bflo(rv.y), acc[b][2]);
                                    acc[b][3] = fmaf(qreg[b][3], bfhi(rv.y), acc[b][3]);
                                    acc[b][4] = fmaf(qreg[b][4], bflo(rv.z), acc[b][4]);
                                    acc[b][5] = fmaf(qreg[b][5], bfhi(rv.z), acc[b][5]);
                                    acc[b][6] = fmaf(qreg[b][6], bflo(rv.w), acc[b][6]);
                                    acc[b][7] = fmaf(qreg[b][7], bfhi(rv.w), acc[b][7]);
                                }
                            }
                        } else {
                            #pragma unroll
                            for (int b = 0; b < 4; b++) {
                                uint4 xv = *reinterpret_cast<const uint4*>(
                                    xbin + ((size_t)(b * NNODES + src)) * 64 + d8 * 8);
                                uint4 rv = *reinterpret_cast<const uint4*>(
                                    ((const u16*)relv) + ((size_t)(b * RR + et)) * 64 + d8 * 8);
                                acc[b][0] = fmaf(bflo(xv.x), bflo(rv.x), acc[b][0]);
                                acc[b][1] = fmaf(bfhi(xv.x), bfhi(rv.x), acc[b][1]);
                                acc[b][2] = fmaf(bflo(xv.y), bflo(rv.y), acc[b][2]);
                                acc[b][3] = fmaf(bfhi(xv.y), bfhi(rv.y), acc[b][3]);
                                acc[b][4] = fmaf(bflo(xv.z), bflo(rv.z), acc[b][4]);
                                acc[b][5] = fmaf(bfhi(xv.z), bfhi(rv.z), acc[b][5]);
                                acc[b][6] = fmaf(bflo(xv.w), bflo(rv.w), acc[b][6]);
                                acc[b][7] = fmaf(bfhi(xv.w), bfhi(rv.w), acc[b][7]);
                            }
                        }
                    } else {
                        const float* re = (const float*)relv;
                        if constexpr (FIRST) {
                            bool m0 = (src == bn0), m1 = (src == bn1),
                                 m2 = (src == bn2), m3 = (src == bn3);
                            if (m0 | m1 | m2 | m3) {
                                float4 r0 = *reinterpret_cast<const float4*>(re + et * 64 + d8 * 8);
                                float4 r1 = *reinterpret_cast<const float4*>(re + et * 64 + d8 * 8 + 4);
                                float rr[8] = {r0.x,r0.y,r0.z,r0.w,r1.x,r1.y,r1.z,r1.w};
                                if (m0) {
                                    #pragma unroll
                                    for (int i = 0; i < 8; i++) acc[0][i] += rr[i];
                                }
                                if (m1) {
                                    #pragma unroll
                                    for (int i = 0; i < 8; i++) acc[1][i] += rr[i];
                                }
                                if (m2) {
                                    #pragma unroll
                                    for (int i = 0; i < 8; i++) acc[2][i] += rr[i];
                                }
                                if (m3) {
                                    #pragma unroll
                                    for (int i = 0; i < 8; i++) acc[3][i] += rr[i];
                                }
                            }
                        } else {
                            float4 r0 = *reinterpret_cast<const float4*>(re + et * 64 + d8 * 8);
                            float4 r1 = *reinterpret_cast<const float4*>(re + et * 64 + d8 * 8 + 4);
                            #pragma unroll
                            for (int b = 0; b < 4; b++) {
                                const float* xr = xin + ((size_t)(b * NNODES + src)) * 64 + d8 * 8;
                                float4 x0 = *reinterpret_cast<const float4*>(xr);
                                float4 x1 = *reinterpret_cast<const float4*>(xr + 4);
                                acc[b][0] = fmaf(x0.x, r0.x, acc[b][0]);
                                acc[b][1] = fmaf(x0.y, r0.y, acc[b][1]);
                                acc[b][2] = fmaf(x0.z, r0.z, acc[b][2]);
                                acc[b][3] = fmaf(x0.w, r0.w, acc[b][3]);
                                acc[b][4] = fmaf(x1.x, r1.x, acc[b][4]);
                                acc[b][5] = fmaf(x1.y, r1.y, acc[b][5]);
                                acc[b][6] = fmaf(x1.z, r1.z, acc[b][6]);
                                acc[b][7] = fmaf(x1.w, r1.w, acc[b][7]);
                            }
                        }
                    }
                }
            }
        }

        #pragma unroll
        for (int b = 0; b < 4; b++)
            #pragma unroll
            for (int i = 0; i < 8; i++) {
                float v = acc[b][i];
                v += __shfl_xor(v, 8);
                v += __shfl_xor(v, 16);
                v += __shfl_xor(v, 32);
                acc[b][i] = v;
            }

        if (slot < 4) {
            float out[8];
            #pragma unroll
            for (int i = 0; i < 8; i++)
                out[i] = (slot==0) ? acc[0][i] : (slot==1) ? acc[1][i]
                       : (slot==2) ? acc[2][i] : acc[3][i];
            int bnb = (slot==0)?bn0:(slot==1)?bn1:(slot==2)?bn2:bn3;
            if (gnode < NNODES && gnode == bnb) {
                if constexpr (MODE == 1) {
                    #pragma unroll
                    for (int i = 0; i < 8; i++)
                        out[i] += (slot==0)?qreg[0][i]:(slot==1)?qreg[1][i]
                                 :(slot==2)?qreg[2][i]:qreg[3][i];
                } else {
                    #pragma unroll
                    for (int i = 0; i < 8; i++) out[i] += 1.0f;
                }
            }
            int m = slot * 4 + wv;
            *reinterpret_cast<uint4*>(&As[m][d8 * 8]) =
                make_uint4(pack2bf(out[0], out[1]), pack2bf(out[2], out[3]),
                           pack2bf(out[4], out[5]), pack2bf(out[6], out[7]));
        }
    }
    __syncthreads();

    // ---- MFMA phase A: As (messages) x W_hi; wave = n-tile ----
    const int al = lane & 15;
    const int ag = lane >> 4;
    const int nt = wv;
    f32x4 acc4 = (f32x4){0.f, 0.f, 0.f, 0.f};
    {
        bf16x8 a0 = *reinterpret_cast<const bf16x8*>(&As[al][ag * 8]);
        bf16x8 a1 = *reinterpret_cast<const bf16x8*>(&As[al][32 + ag * 8]);
        bf16x8 b0 = *reinterpret_cast<const bf16x8*>(&Wt[nt * 16 + al][ag * 8]);
        bf16x8 b1 = *reinterpret_cast<const bf16x8*>(&Wt[nt * 16 + al][32 + ag * 8]);
        acc4 = __builtin_amdgcn_mfma_f32_16x16x32_bf16(a0, b0, acc4, 0, 0, 0);
        acc4 = __builtin_amdgcn_mfma_f32_16x16x32_bf16(a1, b1, acc4, 0, 0, 0);
    }
    __syncthreads();   // Wt reads done before restage

    // ---- restage Wt = W_lo (rows 0..63) ----
    {
        int n = lane, k16 = wv * 16;
        u32 buf[8];
        #pragma unroll
        for (int j2 = 0; j2 < 8; j2++) {
            float w0 = W[(k16 + 2 * j2    ) * 64 + n];
            float w1 = W[(k16 + 2 * j2 + 1) * 64 + n];
            buf[j2] = pack2bf(w0, w1);
        }
        uint4* dst = reinterpret_cast<uint4*>(&Wt[n][k16]);
        dst[0] = make_uint4(buf[0], buf[1], buf[2], buf[3]);
        dst[1] = make_uint4(buf[4], buf[5], buf[6], buf[7]);
    }
    __syncthreads();   // Wt ready

    // ---- MFMA phase B: Xs (x state) x W_lo ----
    {
        bf16x8 x0 = *reinterpret_cast<const bf16x8*>(&Xs[al][ag * 8]);
        bf16x8 x1 = *reinterpret_cast<const bf16x8*>(&Xs[al][32 + ag * 8]);
        bf16x8 b0 = *reinterpret_cast<const bf16x8*>(&Wt[nt * 16 + al][ag * 8]);
        bf16x8 b1 = *reinterpret_cast<const bf16x8*>(&Wt[nt * 16 + al][32 + ag * 8]);
        acc4 = __builtin_amdgcn_mfma_f32_16x16x32_bf16(x0, b0, acc4, 0, 0, 0);
        acc4 = __builtin_amdgcn_mfma_f32_16x16x32_bf16(x1, b1, acc4, 0, 0, 0);
    }
    #pragma unroll
    for (int reg = 0; reg < 4; reg++)
        LNbuf[ag * 4 + reg][nt * 16 + al] = acc4[reg];
    __syncthreads();

    // ---- epilogue: wave wv handles rows wv*4..wv*4+3 (one row / 16 lanes) --
    {
        int row = erow;
        int b = row >> 2, node = node0 + (row & 3);
        float o[4];
        float s1 = 0.f, s2 = 0.f;
        #pragma unroll
        for (int i = 0; i < 4; i++) {
            o[i] = LNbuf[row][tx * 4 + i] + bias[tx * 4 + i];
            s1 += o[i];
            s2 += o[i] * o[i];
        }
        s1 += __shfl_xor(s1, 1); s2 += __shfl_xor(s2, 1);
        s1 += __shfl_xor(s1, 2); s2 += __shfl_xor(s2, 2);
        s1 += __shfl_xor(s1, 4); s2 += __shfl_xor(s2, 4);
        s1 += __shfl_xor(s1, 8); s2 += __shfl_xor(s2, 8);
        float mean = s1 * (1.f / 64.f);
        float var  = s2 * (1.f / 64.f) - mean * mean;
        float inv  = rsqrtf(var + EPS_);
        if (node < NNODES) {
            int bnb = (b==0)?bn0:(b==1)?bn1:(b==2)?bn2:bn3;
            size_t ro = ((size_t)b * NNODES + node) * 64;
            float r[4] = {resf.x, resf.y, resf.z, resf.w};
            if constexpr (FIRST) {
                r[0] = r[1] = r[2] = r[3] = 0.f;
                if (node == bnb) {
                    if constexpr (MODE == 1) {
                        float4 q = *reinterpret_cast<const float4*>(query + b * 64 + tx * 4);
                        r[0] = q.x; r[1] = q.y; r[2] = q.z; r[3] = q.w;
                    } else {
                        r[0] = r[1] = r[2] = r[3] = 1.0f;
                    }
                }
            }
            float nv[4];
            #pragma unroll
            for (int i = 0; i < 4; i++) {
                float h = (o[i] - mean) * inv * gw[tx * 4 + i] + bt[tx * 4 + i];
                h = fmaxf(h, 0.f);
                nv[i] = r[i] + h;
            }
            *reinterpret_cast<float4*>(&xout[ro + tx * 4]) =
                make_float4(nv[0], nv[1], nv[2], nv[3]);
            if constexpr (MODE == 1) {
                ushort4 b4;
                b4.x = f2bf(nv[0]); b4.y = f2bf(nv[1]);
                b4.z = f2bf(nv[2]); b4.w = f2bf(nv[3]);
                *reinterpret_cast<ushort4*>(&xbout[ro + tx * 4]) = b4;
            }
        }
    }
}

// ========== all-layer relation MLP: rel_all[l] = relu(rel_repr@Wp1+b)@Wp2+b (bf16)
__global__ __launch_bounds__(64)
void k_rel_mlp_all(const float* __restrict__ rel_repr,
                   const float* __restrict__ Wp1, const float* __restrict__ bp1,
                   const float* __restrict__ Wp2, const float* __restrict__ bp2,
                   u16* __restrict__ out) {
    __shared__ float rowv[64];
    __shared__ float hid[64];
    int l     = blockIdx.x / (B_ * RR);
    int rowid = blockIdx.x % (B_ * RR);
    int d = threadIdx.x;
    const float* w1 = Wp1 + l * 4096;
    const float* w2 = Wp2 + l * 4096;
    rowv[d] = rel_repr[rowid * 64 + d];
    __syncthreads();
    float acc = bp1[l * 64 + d];
    for (int k = 0; k < 64; k++) acc = fmaf(rowv[k], w1[k * 64 + d], acc);
    hid[d] = fmaxf(acc, 0.f);
    __syncthreads();
    float o = bp2[l * 64 + d];
    for (int k = 0; k < 64; k++) o = fmaf(hid[k], w2[k * 64 + d], o);
    out[(size_t)l * B_ * RR * 64 + rowid * 64 + d] = f2bf(o);
}

// ================= query[b] = rel_repr[b, r_index[b]] ======================
__global__ __launch_bounds__(256)
void k_query(const float* __restrict__ rel_repr, const int* __restrict__ batch,
             float* __restrict__ query) {
    int tid = threadIdx.x;  // 256 = B*64
    int b = tid >> 6;
    int d = tid & 63;
    int r = batch[b * K_ * 3 + 2];
    query[b * 64 + d] = rel_repr[(b * RR + r) * 64 + d];
}

// ================= final MLP over gathered rows ============================
__global__ __launch_bounds__(128)
void k_final(const float* __restrict__ x, const float* __restrict__ query,
             const int* __restrict__ batch,
             const float* __restrict__ W1, const float* __restrict__ b1,
             const float* __restrict__ W2, const float* __restrict__ b2,
             float* __restrict__ out) {
    __shared__ float feat[128];
    __shared__ float partial[2];
    int pair = blockIdx.x;          // b*K + k
    int b = pair / K_;
    int t = batch[pair * 3 + 1];
    int d = threadIdx.x;
    feat[d] = (d < 64) ? x[(size_t)(b * NN + t) * 64 + d] : query[b * 64 + (d - 64)];
    __syncthreads();
    float h = b1[d];
    for (int i = 0; i < 128; i++) h = fmaf(feat[i], W1[i * 128 + d], h);
    h = fmaxf(h, 0.f);
    float v = h * W2[d];
    #pragma unroll
    for (int off = 1; off < 64; off <<= 1) v += __shfl_xor(v, off);
    if ((d & 63) == 0) partial[d >> 6] = v;
    __syncthreads();
    if (d == 0) out[pair] = partial[0] + partial[1] + b2[0];
}

extern "C" void kernel_launch(void* const* d_in, const int* in_sizes, int n_in,
                              void* d_out, int out_size, void* d_ws, size_t ws_size,
                              hipStream_t stream) {
    const int* batch      = (const int*)d_in[0];
    const int* edge_index = (const int*)d_in[1];
    const int* edge_type  = (const int*)d_in[2];
    const int* rel_ei     = (const int*)d_in[3];
    const int* rel_et     = (const int*)d_in[4];
    const float* rel_emb = (const float*)d_in[7];
    const float* Wr  = (const float*)d_in[8];
    const float* br  = (const float*)d_in[9];
    const float* gr  = (const float*)d_in[10];
    const float* btr = (const float*)d_in[11];
    const float* Wp1 = (const float*)d_in[12];
    const float* bp1 = (const float*)d_in[13];
    const float* Wp2 = (const float*)d_in[14];
    const float* bp2 = (const float*)d_in[15];
    const float* We  = (const float*)d_in[16];
    const float* be  = (const float*)d_in[17];
    const float* ge  = (const float*)d_in[18];
    const float* bte = (const float*)d_in[19];
    const float* W1  = (const float*)d_in[20];
    const float* b1  = (const float*)d_in[21];
    const float* W2  = (const float*)d_in[22];
    const float* b2  = (const float*)d_in[23];

    float* ws = (float*)d_ws;
    float* rel_buf0 = ws;                              // 51200
    float* rel_buf1 = rel_buf0 + 51200;                // 51200
    float* query    = rel_buf1 + 51200;                // 256
    float* x0       = query + 256;                     // 5,120,000
    float* x1       = x0 + (size_t)B_ * NN * 64;       // 5,120,000
    u16*   xb0      = (u16*)(x1 + (size_t)B_ * NN * 64);          // 5.12M u16
    u16*   xb1      = xb0 + (size_t)B_ * NN * 64;                 // 5.12M u16
    u16*   rel_all  = xb1 + (size_t)B_ * NN * 64;                 // L*B*RR*64 u16
    int*   iw       = (int*)(rel_all + (size_t)L_ * B_ * RR * 64);

    int* ent_counts  = iw;                        // NN (becomes cursor)
    int* ent_rowptr  = ent_counts + NN;           // NN+1
    int* ent_bsums   = ent_rowptr + NN + 1;       // 32
    int* ent_packed  = ent_bsums + 32;            // EE
    int* rel_counts  = ent_packed + EE;           // RR (becomes cursor)
    int* rel_rowptr  = rel_counts + RR;           // RR+1
    int* rel_bsums   = rel_rowptr + RR + 1;       // 8
    int* rel_packed  = rel_bsums + 8;             // ER_

    const int ENT_NB = (NN + 1023) / 1024;        // 20
    const int REL_NB = (RR + 1023) / 1024;        // 1

    // ---- CSR build (both graphs, 6 dispatches) ----
    k_zero2<<<(NN + RR + 255) / 256, 256, 0, stream>>>(ent_counts, rel_counts);
    k_hist2<<<(EE + ER_ + 255) / 256, 256, 0, stream>>>(edge_index, rel_ei, ent_counts, rel_counts);
    k_scan1_2<<<ENT_NB + REL_NB, 256, 0, stream>>>(ent_counts, ent_rowptr, ent_bsums,
                                                   rel_counts, rel_rowptr, rel_bsums, ENT_NB);
    k_scan2_2<<<1, 64, 0, stream>>>(ent_bsums, ENT_NB, ent_rowptr + NN,
                                    rel_bsums, REL_NB, rel_rowptr + RR);
    k_scan3_2<<<(NN + RR + 255) / 256, 256, 0, stream>>>(ent_rowptr, ent_bsums, ent_counts,
                                                         rel_rowptr, rel_bsums, rel_counts);
    k_fill2<<<(EE + ER_ + 255) / 256, 256, 0, stream>>>(edge_index, edge_type, rel_ei, rel_et,
                                                        ent_counts, rel_counts, ent_packed, rel_packed);

    // ---- relation-graph model (fused layers, double-buffered) ----
    float* rf[2] = {rel_buf0, rel_buf1};
    const int RGRID = (RR + 3) / 4;               // 50
    k_layer9<RR, 0, true><<<RGRID, 256, 0, stream>>>(
        nullptr, rf[0], nullptr, nullptr, rel_emb,
        rel_rowptr, rel_packed, nullptr, batch,
        Wr, br, gr, btr);
    int rc = 0;
    for (int l = 1; l < L_; ++l) {
        k_layer9<RR, 0, false><<<RGRID, 256, 0, stream>>>(
            rf[rc], rf[rc ^ 1], nullptr, nullptr, rel_emb,
            rel_rowptr, rel_packed, nullptr, batch,
            Wr + l * 8192, br + l * 64, gr + l * 64, btr + l * 64);
        rc ^= 1;
    }
    float* rel_final = rf[rc];

    // ---- entity-graph model ----
    k_query<<<1, 256, 0, stream>>>(rel_final, batch, query);
    k_rel_mlp_all<<<L_ * B_ * RR, 64, 0, stream>>>(rel_final, Wp1, bp1, Wp2, bp2, rel_all);
    float* xf[2] = {x0, x1};
    u16*   xh[2] = {xb0, xb1};
    const int EGRID = (NN + 3) / 4;               // 5000
    k_layer9<NN, 1, true><<<EGRID, 256, 0, stream>>>(
        nullptr, xf[0], nullptr, xh[0], rel_all,
        ent_rowptr, ent_packed, query, batch,
        We, be, ge, bte);
    int ec = 0;
    for (int l = 1; l < L_; ++l) {
        k_layer9<NN, 1, false><<<EGRID, 256, 0, stream>>>(
            xf[ec], xf[ec ^ 1], xh[ec], xh[ec ^ 1],
            rel_all + (size_t)l * B_ * RR * 64,
            ent_rowptr, ent_packed, query, batch,
            We + l * 8192, be + l * 64, ge + l * 64, bte + l * 64);
        ec ^= 1;
    }
    k_final<<<B_ * K_, 128, 0, stream>>>(xf[ec], query, batch, W1, b1, W2, b2,
                                         (float*)d_out);
}